// Round 14
// baseline (70.245 us; speedup 1.0000x reference)
//
#include <hip/hip_runtime.h>

// GatingNetwork: router GEMM via 3-term bf16-split MFMA + fused softmax/double top-k
// Round 14: ROWS=64 (4 row-groups/wave, acc[4][4]) -> B traffic 384->192 MB.
// Rationale: r5->r6 (B 768->384 MB) was the only structural win (80->46us, ~11 TB/s
// effective B delivery); all scheduling knobs (waves, order, regcap) returned flat.
// Grid 256 x 512thr, 1 block/CU, cap 256 (r12: no spill at this cap).
// x: [16384, 2048] f32, W: [64, 2048] f32
// out (f32 flat): topk_idx[16384,2] | topk_weights[16384,2] | probs[16384,64] | topc_idx[16384,8]

typedef __attribute__((ext_vector_type(8))) short short8;   // 8 bf16 = 4 VGPR (MFMA A/B frag)
typedef __attribute__((ext_vector_type(4))) float f32x4;    // MFMA C/D frag

constexpr int Bq = 16384;
constexpr int Dk = 2048;
constexpr int Me = 64;
constexpr int WAVES = 8;
constexpr int ROWS = 64;             // rows per block (all waves share them)
constexpr int KCHUNK = Dk / WAVES;   // 256
constexpr int NT = KCHUNK / 32;      // 8 k-tiles per wave
constexpr int XLD = 34;              // xa row stride (pad: 2-way read banks = free)

constexpr size_t OFF_TOPK_IDX = 0;
constexpr size_t OFF_TOPK_W   = (size_t)Bq * 2;
constexpr size_t OFF_PROBS    = (size_t)Bq * 4;
constexpr size_t OFF_TOPC_IDX = (size_t)Bq * 4 + (size_t)Bq * 64;

// packed f32x2 -> 2 bf16 (RNE, v_cvt_pk_bf16_f32); low16 = lo, high16 = hi
__device__ __forceinline__ unsigned f2bf2(float lo, float hi) {
  unsigned r;
  asm("v_cvt_pk_bf16_f32 %0, %1, %2" : "=v"(r) : "v"(lo), "v"(hi));
  return r;
}
__device__ __forceinline__ float bflo(unsigned u) { return __builtin_bit_cast(float, u << 16); }
__device__ __forceinline__ float bfhi(unsigned u) { return __builtin_bit_cast(float, u & 0xFFFF0000u); }

// split 8 f32 -> 3 short8 bf16 fragments (telescoping residuals)
__device__ __forceinline__ void split3(const float af[8], short8& s0, short8& s1, short8& s2) {
  uint4 q0, q1, q2;
  unsigned* p0 = &q0.x; unsigned* p1 = &q1.x; unsigned* p2 = &q2.x;
  #pragma unroll
  for (int p = 0; p < 4; ++p) {
    float a = af[2 * p], b = af[2 * p + 1];
    unsigned c0 = f2bf2(a, b);
    float r0a = a - bflo(c0), r0b = b - bfhi(c0);
    unsigned c1 = f2bf2(r0a, r0b);
    float r1a = r0a - bflo(c1), r1b = r0b - bfhi(c1);
    unsigned c2 = f2bf2(r1a, r1b);
    p0[p] = c0; p1[p] = c1; p2[p] = c2;
  }
  s0 = __builtin_bit_cast(short8, q0);
  s1 = __builtin_bit_cast(short8, q1);
  s2 = __builtin_bit_cast(short8, q2);
}

// ---- prep: split W f32 -> 3 bf16 planes, FRAGMENT-PACKED: [kt][n][lane][8] ----
// element (kt,n,L,j) = W[n*16 + (L&15)][kt*32 + (L>>4)*8 + j]
__global__ void wsplit_kernel(const float* __restrict__ W,
                              unsigned short* __restrict__ w0,
                              unsigned short* __restrict__ w1,
                              unsigned short* __restrict__ w2) {
  int t = blockIdx.x * blockDim.x + threadIdx.x;  // 0..16383
  int kt = t >> 8, n = (t >> 6) & 3, L = t & 63;
  int e  = n * 16 + (L & 15);
  int kb = kt * 32 + ((L >> 4) << 3);
  const float* src = W + (size_t)e * Dk + kb;
  float4 a = *reinterpret_cast<const float4*>(src);
  float4 b = *reinterpret_cast<const float4*>(src + 4);
  float af[8] = {a.x, a.y, a.z, a.w, b.x, b.y, b.z, b.w};
  short8 s0, s1, s2;
  split3(af, s0, s1, s2);
  *reinterpret_cast<short8*>(w0 + (size_t)t * 8) = s0;
  *reinterpret_cast<short8*>(w1 + (size_t)t * 8) = s1;
  *reinterpret_cast<short8*>(w2 + (size_t)t * 8) = s2;
}

// ---- main: 512 threads = 8 waves; all waves share 64 rows, each owns 1/8 of K ----
__global__ __launch_bounds__(512, 1)
void gating_mfma(const float* __restrict__ x,
                 const unsigned short* __restrict__ w0,
                 const unsigned short* __restrict__ w1,
                 const unsigned short* __restrict__ w2,
                 float* __restrict__ out) {
  // overlay: xa[8][64][34] f32 (69632B); then part[4][64][68] f32 (69632B)
  __shared__ __align__(16) char smem[WAVES * ROWS * XLD * 4];
  typedef float XaT[ROWS][XLD];
  XaT* xa = reinterpret_cast<XaT*>(smem);        // xa[wv][row][col]
  typedef float PartT[ROWS][68];
  PartT* part = reinterpret_cast<PartT*>(smem);  // part[0..3][row][col]

  const int tid  = threadIdx.x;
  const int wv   = tid >> 6;      // wave id = K-chunk id (0..7)
  const int L    = tid & 63;
  const int lidx = L & 15;        // A: row within 16-group; B: expert within N-tile
  const int kgrp = L >> 4;        // k-octet group 0..3
  const int rowBase = blockIdx.x * ROWS;
  const int kBase = wv * KCHUNK;

  // staging lane mapping: lane L covers rows (s*8 + L>>3), 128B contiguous per row
  const int srow = L >> 3;           // 0..7
  const int sc4  = (L & 7) << 2;     // f32 col 0,4,..,28
  const float* xgb = x + (size_t)(rowBase + srow) * Dk + kBase + sc4;

  // B fragment base (shorts): global tile ktg -> ktg*2048 + n*512 + L*8
  const size_t bbase = (size_t)kBase * 64 + (size_t)L * 8;

  f32x4 acc[4][4];
  #pragma unroll
  for (int rg = 0; rg < 4; ++rg)
    #pragma unroll
    for (int n = 0; n < 4; ++n) acc[rg][n] = (f32x4){0.f, 0.f, 0.f, 0.f};

  // prologue: tile0 -> LDS (wave-private region, no barrier needed)
  #pragma unroll
  for (int s = 0; s < 8; ++s)
    *reinterpret_cast<float4*>(&xa[wv][s * 8 + srow][sc4]) =
        *reinterpret_cast<const float4*>(xgb + (size_t)s * 8 * Dk);

  #pragma unroll 1
  for (int kt = 0; kt < NT; ++kt) {
    // A fragments for all 4 row-groups
    float4 aLo[4], aHi[4];
    #pragma unroll
    for (int rg = 0; rg < 4; ++rg) {
      aLo[rg] = *reinterpret_cast<const float4*>(&xa[wv][rg * 16 + lidx][kgrp * 8]);
      aHi[rg] = *reinterpret_cast<const float4*>(&xa[wv][rg * 16 + lidx][kgrp * 8 + 4]);
    }

    // issue next-tile global loads early (written late, after MFMAs)
    float4 h[8];
    if (kt < NT - 1) {
      #pragma unroll
      for (int s = 0; s < 8; ++s)
        h[s] = *reinterpret_cast<const float4*>(xgb + (size_t)s * 8 * Dk + (kt + 1) * 32);
    }

    const size_t to = bbase + (size_t)kt * 2048;

    // plane-0 B loads
    short8 b0[4];
    #pragma unroll
    for (int n = 0; n < 4; ++n) b0[n] = *reinterpret_cast<const short8*>(w0 + to + n * 512);

    // split all 4 A octets into 3 bf16 fragments each
    short8 xs0[4], xs1[4], xs2[4];   // xs<plane>[rowgroup]
    #pragma unroll
    for (int rg = 0; rg < 4; ++rg) {
      float af[8] = {aLo[rg].x, aLo[rg].y, aLo[rg].z, aLo[rg].w,
                     aHi[rg].x, aHi[rg].y, aHi[rg].z, aHi[rg].w};
      split3(af, xs0[rg], xs1[rg], xs2[rg]);
    }

    // plane-1 B loads before plane-0 MFMA cluster (latency overlap)
    short8 b1[4];
    #pragma unroll
    for (int n = 0; n < 4; ++n) b1[n] = *reinterpret_cast<const short8*>(w1 + to + n * 512);

    // plane 0: x0*W0, x1*W0, x2*W0 for 4 row-groups (48 MFMA)
    #pragma unroll
    for (int rg = 0; rg < 4; ++rg)
      #pragma unroll
      for (int n = 0; n < 4; ++n)
        acc[rg][n] = __builtin_amdgcn_mfma_f32_16x16x32_bf16(xs0[rg], b0[n], acc[rg][n], 0, 0, 0);
    #pragma unroll
    for (int rg = 0; rg < 4; ++rg)
      #pragma unroll
      for (int n = 0; n < 4; ++n)
        acc[rg][n] = __builtin_amdgcn_mfma_f32_16x16x32_bf16(xs1[rg], b0[n], acc[rg][n], 0, 0, 0);
    #pragma unroll
    for (int rg = 0; rg < 4; ++rg)
      #pragma unroll
      for (int n = 0; n < 4; ++n)
        acc[rg][n] = __builtin_amdgcn_mfma_f32_16x16x32_bf16(xs2[rg], b0[n], acc[rg][n], 0, 0, 0);

    // plane-2 B loads before plane-1 MFMA cluster
    short8 b2[4];
    #pragma unroll
    for (int n = 0; n < 4; ++n) b2[n] = *reinterpret_cast<const short8*>(w2 + to + n * 512);

    // plane 1: x0*W1, x1*W1 (32 MFMA)
    #pragma unroll
    for (int rg = 0; rg < 4; ++rg)
      #pragma unroll
      for (int n = 0; n < 4; ++n)
        acc[rg][n] = __builtin_amdgcn_mfma_f32_16x16x32_bf16(xs0[rg], b1[n], acc[rg][n], 0, 0, 0);
    #pragma unroll
    for (int rg = 0; rg < 4; ++rg)
      #pragma unroll
      for (int n = 0; n < 4; ++n)
        acc[rg][n] = __builtin_amdgcn_mfma_f32_16x16x32_bf16(xs1[rg], b1[n], acc[rg][n], 0, 0, 0);

    // plane 2: x0*W2 (16 MFMA)
    #pragma unroll
    for (int rg = 0; rg < 4; ++rg)
      #pragma unroll
      for (int n = 0; n < 4; ++n)
        acc[rg][n] = __builtin_amdgcn_mfma_f32_16x16x32_bf16(xs0[rg], b2[n], acc[rg][n], 0, 0, 0);

    // write-late: next A tile into the wave-private buffer
    if (kt < NT - 1) {
      #pragma unroll
      for (int s = 0; s < 8; ++s)
        *reinterpret_cast<float4*>(&xa[wv][s * 8 + srow][sc4]) = h[s];
    }
  }

  // ---- two-stage K-reduce: 8 partials -> 4 (LDS) -> epilogue sums 4 ----
  // D layout: row = rg*16 + kgrp*4 + r, col = n*16 + lidx  [m89-verified]
  __syncthreads();  // xa dead everywhere; part overlays it
  if (wv >= 4) {
    #pragma unroll
    for (int rg = 0; rg < 4; ++rg)
      #pragma unroll
      for (int n = 0; n < 4; ++n)
        #pragma unroll
        for (int r = 0; r < 4; ++r)
          part[wv - 4][rg * 16 + kgrp * 4 + r][n * 16 + lidx] = acc[rg][n][r];
  }
  __syncthreads();
  if (wv < 4) {
    #pragma unroll
    for (int rg = 0; rg < 4; ++rg)
      #pragma unroll
      for (int n = 0; n < 4; ++n)
        #pragma unroll
        for (int r = 0; r < 4; ++r) {
          float s = acc[rg][n][r] + part[wv][rg * 16 + kgrp * 4 + r][n * 16 + lidx];
          part[wv][rg * 16 + kgrp * 4 + r][n * 16 + lidx] = s;
        }
  }
  __syncthreads();

  // ---- epilogue: 8 threads per row (64 rows x 8 = 512), each owns 8 logit cols ----
  const int row = tid >> 3;        // 0..63
  const int g   = tid & 7;
  const int c8  = g * 8;
  const size_t grow = (size_t)rowBase + row;

  float pv[8];
  {
    float4 va = {0.f, 0.f, 0.f, 0.f}, vb = {0.f, 0.f, 0.f, 0.f};
    #pragma unroll
    for (int p = 0; p < 4; ++p) {
      float4 ta = *reinterpret_cast<const float4*>(&part[p][row][c8]);
      float4 tb = *reinterpret_cast<const float4*>(&part[p][row][c8 + 4]);
      va.x += ta.x; va.y += ta.y; va.z += ta.z; va.w += ta.w;
      vb.x += tb.x; vb.y += tb.y; vb.z += tb.z; vb.w += tb.w;
    }
    pv[0] = va.x; pv[1] = va.y; pv[2] = va.z; pv[3] = va.w;
    pv[4] = vb.x; pv[5] = vb.y; pv[6] = vb.z; pv[7] = vb.w;
  }

  // softmax over 64 via width-8 butterflies (masks <8 stay within row-group)
  float mx = pv[0];
  #pragma unroll
  for (int j = 1; j < 8; ++j) mx = fmaxf(mx, pv[j]);
  #pragma unroll
  for (int m = 1; m < 8; m <<= 1) mx = fmaxf(mx, __shfl_xor(mx, m));
  float e[8], sum = 0.f;
  #pragma unroll
  for (int j = 0; j < 8; ++j) { e[j] = expf(pv[j] - mx); sum += e[j]; }
  #pragma unroll
  for (int m = 1; m < 8; m <<= 1) sum += __shfl_xor(sum, m);
  const float inv = 1.f / (sum + 1e-12f);
  float4 pwa = {e[0] * inv, e[1] * inv, e[2] * inv, e[3] * inv};
  float4 pwb = {e[4] * inv, e[5] * inv, e[6] * inv, e[7] * inv};
  *reinterpret_cast<float4*>(out + OFF_PROBS + grow * 64 + c8) = pwa;
  *reinterpret_cast<float4*>(out + OFF_PROBS + grow * 64 + c8 + 4) = pwb;

  // top-8: 8 masked argmax passes; tie-break = lowest index (matches jax/np)
  unsigned taken = 0;
  int bidx0 = 0, bidx1 = 0;
  float tv0 = 0.f, tv1 = 0.f;
  #pragma unroll 1
  for (int rank = 0; rank < 8; ++rank) {
    float best = -3.4e38f;
    int bl = -1;
    #pragma unroll
    for (int j = 0; j < 8; ++j)
      if (!((taken >> j) & 1u) && pv[j] > best) { best = pv[j]; bl = j; }
    int bidx = (bl >= 0) ? (c8 + bl) : (1 << 30);
    #pragma unroll
    for (int m = 1; m < 8; m <<= 1) {
      float ov = __shfl_xor(best, m);
      int   oi = __shfl_xor(bidx, m);
      if (ov > best || (ov == best && oi < bidx)) { best = ov; bidx = oi; }
    }
    if (bidx >= c8 && bidx < c8 + 8) taken |= 1u << (bidx - c8);
    if (g == 0) out[OFF_TOPC_IDX + grow * 8 + rank] = (float)bidx;
    if (rank == 0) { tv0 = best; bidx0 = bidx; }
    if (rank == 1) { tv1 = best; bidx1 = bidx; }
  }

  if (g == 0) {
    out[OFF_TOPK_IDX + grow * 2 + 0] = (float)bidx0;
    out[OFF_TOPK_IDX + grow * 2 + 1] = (float)bidx1;
    const float e1  = expf(tv1 - tv0);
    const float den = 1.f + e1 + 1e-12f;
    out[OFF_TOPK_W + grow * 2 + 0] = 1.f / den;
    out[OFF_TOPK_W + grow * 2 + 1] = e1 / den;
  }
}

extern "C" void kernel_launch(void* const* d_in, const int* in_sizes, int n_in,
                              void* d_out, int out_size, void* d_ws, size_t ws_size,
                              hipStream_t stream) {
  const float* x = (const float*)d_in[0];
  const float* W = (const float*)d_in[1];
  float* out = (float*)d_out;

  unsigned short* w0 = (unsigned short*)d_ws;
  unsigned short* w1 = w0 + (size_t)Me * Dk;
  unsigned short* w2 = w1 + (size_t)Me * Dk;

  hipLaunchKernelGGL(wsplit_kernel, dim3((Me * Dk / 8) / 256), dim3(256), 0, stream, W, w0, w1, w2);
  hipLaunchKernelGGL(gating_mfma, dim3(Bq / ROWS), dim3(512), 0, stream, x, w0, w1, w2, out);
}

// Round 16
// 41.311 us; speedup vs baseline: 1.7004x; 1.7004x over previous
//
#include <hip/hip_runtime.h>

// GatingNetwork: router GEMM via 2-term f16-split MFMA + fused softmax/double top-k
// Round 16: round-15 design with compile fix (cvt_pkrtz returns __fp16x2, bit_cast
// into packed words). f16 has 10 mantissa bits, so a 2-term split with 3 kept
// products (x0W0,x1W0,x0W1; error ~2^-20/term ~ 3e-6 logit) replaces the bf16
// 3-term/6-product scheme. At the r13 skeleton (46.08us): MFMA count x0.5, B
// traffic 384->256MB, split VALU ~x0.55. The 46us plateau behaved as the serial
// sum of pipe floors (r6-r14: all scheduling knobs flat) -- shrink the terms.
// x: [16384, 2048] f32, W: [64, 2048] f32
// out (f32 flat): topk_idx[16384,2] | topk_weights[16384,2] | probs[16384,64] | topc_idx[16384,8]

typedef __fp16 fp16x2 __attribute__((ext_vector_type(2)));      // cvt_pkrtz result type
typedef _Float16 half8_t __attribute__((ext_vector_type(8)));   // 8 f16 = 4 VGPR (MFMA A/B frag)
typedef __attribute__((ext_vector_type(4))) float f32x4;        // MFMA C/D frag

constexpr int Bq = 16384;
constexpr int Dk = 2048;
constexpr int Me = 64;
constexpr int WAVES = 8;
constexpr int ROWS = 32;             // rows per block (all waves share them)
constexpr int KCHUNK = Dk / WAVES;   // 256
constexpr int NT = KCHUNK / 32;      // 8 k-tiles per wave

constexpr size_t OFF_TOPK_IDX = 0;
constexpr size_t OFF_TOPK_W   = (size_t)Bq * 2;
constexpr size_t OFF_PROBS    = (size_t)Bq * 4;
constexpr size_t OFF_TOPC_IDX = (size_t)Bq * 4 + (size_t)Bq * 64;

// split 8 f32 -> 2 half8 f16 fragments (x = x0 + x1 + eps, eps ~ 2^-20 |x|)
// cvt_pkrtz: packed f32x2 -> f16x2 round-toward-zero; residual r = a - (f32)x0 is
// exact (Sterbenz), x1 = rtz(r) leaves eps < 2^-10|r| < 2^-20|a|.
__device__ __forceinline__ void split2(const float af[8], half8_t& s0, half8_t& s1) {
  uint4 q0, q1;
  unsigned* p0 = &q0.x; unsigned* p1 = &q1.x;
  #pragma unroll
  for (int p = 0; p < 4; ++p) {
    float a = af[2 * p], b = af[2 * p + 1];
    fp16x2 c0 = __builtin_amdgcn_cvt_pkrtz(a, b);
    float ra = a - (float)c0[0], rb = b - (float)c0[1];
    fp16x2 c1 = __builtin_amdgcn_cvt_pkrtz(ra, rb);
    p0[p] = __builtin_bit_cast(unsigned, c0);
    p1[p] = __builtin_bit_cast(unsigned, c1);
  }
  s0 = __builtin_bit_cast(half8_t, q0);
  s1 = __builtin_bit_cast(half8_t, q1);
}

// ---- prep: split W f32 -> 2 f16 planes, FRAGMENT-PACKED: [kt][n][lane][8] ----
// element (kt,n,L,j) = W[n*16 + (L&15)][kt*32 + (L>>4)*8 + j]
__global__ void wsplit_kernel(const float* __restrict__ W,
                              unsigned short* __restrict__ w0,
                              unsigned short* __restrict__ w1) {
  int t = blockIdx.x * blockDim.x + threadIdx.x;  // 0..16383
  int kt = t >> 8, n = (t >> 6) & 3, L = t & 63;
  int e  = n * 16 + (L & 15);
  int kb = kt * 32 + ((L >> 4) << 3);
  const float* src = W + (size_t)e * Dk + kb;
  float4 a = *reinterpret_cast<const float4*>(src);
  float4 b = *reinterpret_cast<const float4*>(src + 4);
  float af[8] = {a.x, a.y, a.z, a.w, b.x, b.y, b.z, b.w};
  half8_t s0, s1;
  split2(af, s0, s1);
  *reinterpret_cast<half8_t*>(w0 + (size_t)t * 8) = s0;
  *reinterpret_cast<half8_t*>(w1 + (size_t)t * 8) = s1;
}

// ---- main: 512 threads = 8 waves; all waves share 32 rows, each owns 1/8 of K ----
__global__ __launch_bounds__(512, 2)
void gating_mfma(const float* __restrict__ x,
                 const unsigned short* __restrict__ w0,
                 const unsigned short* __restrict__ w1,
                 float* __restrict__ out) {
  // overlay: A-stage xa[8][32][36] f32 (36864B); then part[4][32][68] f32 (34816B)
  __shared__ __align__(16) char smem[WAVES * ROWS * 36 * 4];  // 36864
  typedef float XaT[ROWS][36];
  XaT* xa = reinterpret_cast<XaT*>(smem);        // xa[wv][row][col]
  typedef float PartT[ROWS][68];
  PartT* part = reinterpret_cast<PartT*>(smem);  // part[0..3][row][col]

  const int tid  = threadIdx.x;
  const int wv   = tid >> 6;      // wave id = K-chunk id (0..7)
  const int L    = tid & 63;
  const int lidx = L & 15;        // A: row within 16-group; B: expert within N-tile
  const int kgrp = L >> 4;        // k-octet group 0..3
  const int rowBase = blockIdx.x * ROWS;
  const int kBase = wv * KCHUNK;

  // staging lane mapping: segment i covers rows i*8..i*8+7, 128B contiguous per row
  const int srow = L >> 3;           // 0..7
  const int sc4  = (L & 7) << 2;     // f32 col 0,4,..,28
  const float* xg0 = x + (size_t)(rowBase +      srow) * Dk + kBase + sc4;
  const float* xg1 = x + (size_t)(rowBase +  8 + srow) * Dk + kBase + sc4;
  const float* xg2 = x + (size_t)(rowBase + 16 + srow) * Dk + kBase + sc4;
  const float* xg3 = x + (size_t)(rowBase + 24 + srow) * Dk + kBase + sc4;

  // B fragment base (shorts): global tile ktg -> ktg*2048 + n*512 + L*8
  const size_t bbase = (size_t)kBase * 64 + (size_t)L * 8;

  f32x4 acc[2][4];
  #pragma unroll
  for (int rg = 0; rg < 2; ++rg)
    #pragma unroll
    for (int n = 0; n < 4; ++n) acc[rg][n] = (f32x4){0.f, 0.f, 0.f, 0.f};

  // prologue: tile0 -> LDS (wave-private region, no barrier needed)
  *reinterpret_cast<float4*>(&xa[wv][     srow][sc4]) = *reinterpret_cast<const float4*>(xg0);
  *reinterpret_cast<float4*>(&xa[wv][ 8 + srow][sc4]) = *reinterpret_cast<const float4*>(xg1);
  *reinterpret_cast<float4*>(&xa[wv][16 + srow][sc4]) = *reinterpret_cast<const float4*>(xg2);
  *reinterpret_cast<float4*>(&xa[wv][24 + srow][sc4]) = *reinterpret_cast<const float4*>(xg3);

  #pragma unroll 1
  for (int kt = 0; kt < NT; ++kt) {
    // A fragments for both row-groups (reads complete before the write-late below)
    float4 aLo0 = *reinterpret_cast<const float4*>(&xa[wv][     lidx][kgrp * 8]);
    float4 aHi0 = *reinterpret_cast<const float4*>(&xa[wv][     lidx][kgrp * 8 + 4]);
    float4 aLo1 = *reinterpret_cast<const float4*>(&xa[wv][16 + lidx][kgrp * 8]);
    float4 aHi1 = *reinterpret_cast<const float4*>(&xa[wv][16 + lidx][kgrp * 8 + 4]);

    // issue next-tile global loads early (latency hides under MFMA; written late)
    float4 h0, h1, h2, h3;
    if (kt < NT - 1) {
      h0 = *reinterpret_cast<const float4*>(xg0 + (kt + 1) * 32);
      h1 = *reinterpret_cast<const float4*>(xg1 + (kt + 1) * 32);
      h2 = *reinterpret_cast<const float4*>(xg2 + (kt + 1) * 32);
      h3 = *reinterpret_cast<const float4*>(xg3 + (kt + 1) * 32);
    }

    const size_t to = bbase + (size_t)kt * 2048;

    // plane-0 B loads
    half8_t b0[4];
    #pragma unroll
    for (int n = 0; n < 4; ++n) b0[n] = *reinterpret_cast<const half8_t*>(w0 + to + n * 512);

    // split both A octets into 2 f16 fragments each
    float af0[8] = {aLo0.x, aLo0.y, aLo0.z, aLo0.w, aHi0.x, aHi0.y, aHi0.z, aHi0.w};
    float af1[8] = {aLo1.x, aLo1.y, aLo1.z, aLo1.w, aHi1.x, aHi1.y, aHi1.z, aHi1.w};
    half8_t xs00, xs10, xs01, xs11;   // xs<plane><rowgroup>
    split2(af0, xs00, xs10);
    split2(af1, xs01, xs11);

    // plane-1 B loads issued before plane-0 MFMA cluster (latency overlap)
    half8_t b1[4];
    #pragma unroll
    for (int n = 0; n < 4; ++n) b1[n] = *reinterpret_cast<const half8_t*>(w1 + to + n * 512);

    // plane 0: x0*W0, x1*W0 for both row-groups (16 MFMA)
    #pragma unroll
    for (int n = 0; n < 4; ++n) acc[0][n] = __builtin_amdgcn_mfma_f32_16x16x32_f16(xs00, b0[n], acc[0][n], 0, 0, 0);
    #pragma unroll
    for (int n = 0; n < 4; ++n) acc[1][n] = __builtin_amdgcn_mfma_f32_16x16x32_f16(xs01, b0[n], acc[1][n], 0, 0, 0);
    #pragma unroll
    for (int n = 0; n < 4; ++n) acc[0][n] = __builtin_amdgcn_mfma_f32_16x16x32_f16(xs10, b0[n], acc[0][n], 0, 0, 0);
    #pragma unroll
    for (int n = 0; n < 4; ++n) acc[1][n] = __builtin_amdgcn_mfma_f32_16x16x32_f16(xs11, b0[n], acc[1][n], 0, 0, 0);

    // plane 1: x0*W1 (8 MFMA)
    #pragma unroll
    for (int n = 0; n < 4; ++n) acc[0][n] = __builtin_amdgcn_mfma_f32_16x16x32_f16(xs00, b1[n], acc[0][n], 0, 0, 0);
    #pragma unroll
    for (int n = 0; n < 4; ++n) acc[1][n] = __builtin_amdgcn_mfma_f32_16x16x32_f16(xs01, b1[n], acc[1][n], 0, 0, 0);

    // write-late: next A tile into the (single) wave-private buffer
    if (kt < NT - 1) {
      *reinterpret_cast<float4*>(&xa[wv][     srow][sc4]) = h0;
      *reinterpret_cast<float4*>(&xa[wv][ 8 + srow][sc4]) = h1;
      *reinterpret_cast<float4*>(&xa[wv][16 + srow][sc4]) = h2;
      *reinterpret_cast<float4*>(&xa[wv][24 + srow][sc4]) = h3;
    }
  }

  // ---- two-stage K-reduce: 8 partials -> 4 (LDS) -> epilogue sums 4 ----
  // D layout: row = rg*16 + kgrp*4 + r, col = n*16 + lidx  [m89-verified]
  __syncthreads();  // xa dead everywhere; part overlays it
  if (wv >= 4) {
    #pragma unroll
    for (int rg = 0; rg < 2; ++rg)
      #pragma unroll
      for (int n = 0; n < 4; ++n)
        #pragma unroll
        for (int r = 0; r < 4; ++r)
          part[wv - 4][rg * 16 + kgrp * 4 + r][n * 16 + lidx] = acc[rg][n][r];
  }
  __syncthreads();
  if (wv < 4) {
    #pragma unroll
    for (int rg = 0; rg < 2; ++rg)
      #pragma unroll
      for (int n = 0; n < 4; ++n)
        #pragma unroll
        for (int r = 0; r < 4; ++r) {
          float s = acc[rg][n][r] + part[wv][rg * 16 + kgrp * 4 + r][n * 16 + lidx];
          part[wv][rg * 16 + kgrp * 4 + r][n * 16 + lidx] = s;
        }
  }
  __syncthreads();

  // ---- epilogue: 16 threads per row, each owns 4 logit columns ----
  const int row = tid >> 4;        // 0..31
  const int g   = tid & 15;
  const int c4  = g * 4;
  const size_t grow = (size_t)rowBase + row;

  float4 v = {0.f, 0.f, 0.f, 0.f};
  #pragma unroll
  for (int p = 0; p < 4; ++p) {
    float4 t = *reinterpret_cast<const float4*>(&part[p][row][c4]);
    v.x += t.x; v.y += t.y; v.z += t.z; v.w += t.w;
  }
  float pv[4] = {v.x, v.y, v.z, v.w};

  // softmax over 64 via width-16 butterflies
  float mx = fmaxf(fmaxf(pv[0], pv[1]), fmaxf(pv[2], pv[3]));
  #pragma unroll
  for (int m = 1; m < 16; m <<= 1) mx = fmaxf(mx, __shfl_xor(mx, m));
  float e[4], sum = 0.f;
  #pragma unroll
  for (int j = 0; j < 4; ++j) { e[j] = expf(pv[j] - mx); sum += e[j]; }
  #pragma unroll
  for (int m = 1; m < 16; m <<= 1) sum += __shfl_xor(sum, m);
  const float inv = 1.f / (sum + 1e-12f);
  float4 pw = {e[0] * inv, e[1] * inv, e[2] * inv, e[3] * inv};
  *reinterpret_cast<float4*>(out + OFF_PROBS + grow * 64 + c4) = pw;

  // top-8: 8 masked argmax passes; tie-break = lowest index (matches jax/np)
  unsigned taken = 0;
  int bidx0 = 0, bidx1 = 0;
  float tv0 = 0.f, tv1 = 0.f;
  #pragma unroll 1
  for (int rank = 0; rank < 8; ++rank) {
    float best = -3.4e38f;
    int bl = -1;
    #pragma unroll
    for (int j = 0; j < 4; ++j)
      if (!((taken >> j) & 1u) && pv[j] > best) { best = pv[j]; bl = j; }
    int bidx = (bl >= 0) ? (c4 + bl) : (1 << 30);
    #pragma unroll
    for (int m = 1; m < 16; m <<= 1) {
      float ov = __shfl_xor(best, m);
      int   oi = __shfl_xor(bidx, m);
      if (ov > best || (ov == best && oi < bidx)) { best = ov; bidx = oi; }
    }
    if (bidx >= c4 && bidx < c4 + 4) taken |= 1u << (bidx - c4);
    if (g == 0) out[OFF_TOPC_IDX + grow * 8 + rank] = (float)bidx;
    if (rank == 0) { tv0 = best; bidx0 = bidx; }
    if (rank == 1) { tv1 = best; bidx1 = bidx; }
  }

  if (g == 0) {
    out[OFF_TOPK_IDX + grow * 2 + 0] = (float)bidx0;
    out[OFF_TOPK_IDX + grow * 2 + 1] = (float)bidx1;
    const float e1  = expf(tv1 - tv0);
    const float den = 1.f + e1 + 1e-12f;
    out[OFF_TOPK_W + grow * 2 + 0] = 1.f / den;
    out[OFF_TOPK_W + grow * 2 + 1] = e1 / den;
  }
}

extern "C" void kernel_launch(void* const* d_in, const int* in_sizes, int n_in,
                              void* d_out, int out_size, void* d_ws, size_t ws_size,
                              hipStream_t stream) {
  const float* x = (const float*)d_in[0];
  const float* W = (const float*)d_in[1];
  float* out = (float*)d_out;

  unsigned short* w0 = (unsigned short*)d_ws;
  unsigned short* w1 = w0 + (size_t)Me * Dk;

  hipLaunchKernelGGL(wsplit_kernel, dim3((Me * Dk / 8) / 256), dim3(256), 0, stream, W, w0, w1);
  hipLaunchKernelGGL(gating_mfma, dim3(Bq / ROWS), dim3(512), 0, stream, x, w0, w1, out);
}